// Round 2
// baseline (3634.880 us; speedup 1.0000x reference)
//
#include <hip/hip_runtime.h>
#include <math.h>

// Problem constants
#define TEMP 0.7f
#define TOPK 50
#define TOPP 0.9f
#define M_TOT 2048      // B*S = 2*1024
#define K_DIM 512       // H
#define V_DIM 50257     // vocab

// ------------------------- GEMM (f32, tiled) -------------------------
// C[m][v] = (dot(x[m,:], W[v,:]) + b[v]) / TEMP, written into d_out.
#define BM 64
#define BN 64
#define BK 32
#define TM 4
#define TN 4

__global__ __launch_bounds__(256) void gemm_kernel(
    const float* __restrict__ X, const float* __restrict__ W,
    const float* __restrict__ Bv, float* __restrict__ C) {
  __shared__ float As[BM][BK + 1];
  __shared__ float Bs[BN][BK + 1];

  const int bm = blockIdx.y * BM;
  const int bn = blockIdx.x * BN;
  const int tid = threadIdx.x;
  const int tr = tid / 16;
  const int tc = tid % 16;
  const int tm0 = tr * TM;
  const int tn0 = tc * TN;

  float acc[TM][TN];
#pragma unroll
  for (int i = 0; i < TM; ++i)
#pragma unroll
    for (int j = 0; j < TN; ++j) acc[i][j] = 0.f;

  const int lk = tid % BK;
  const int lr = tid / BK;

  for (int k0 = 0; k0 < K_DIM; k0 += BK) {
#pragma unroll
    for (int r = 0; r < BM; r += 8) {
      As[lr + r][lk] = X[(size_t)(bm + lr + r) * K_DIM + k0 + lk];
    }
#pragma unroll
    for (int r = 0; r < BN; r += 8) {
      int n = bn + lr + r;
      Bs[lr + r][lk] = (n < V_DIM) ? W[(size_t)n * K_DIM + k0 + lk] : 0.f;
    }
    __syncthreads();
#pragma unroll
    for (int k = 0; k < BK; ++k) {
      float a[TM], bb[TN];
#pragma unroll
      for (int i = 0; i < TM; ++i) a[i] = As[tm0 + i][k];
#pragma unroll
      for (int j = 0; j < TN; ++j) bb[j] = Bs[tn0 + j][k];
#pragma unroll
      for (int i = 0; i < TM; ++i)
#pragma unroll
        for (int j = 0; j < TN; ++j) acc[i][j] += a[i] * bb[j];
    }
    __syncthreads();
  }

#pragma unroll
  for (int i = 0; i < TM; ++i) {
    int m = bm + tm0 + i;
#pragma unroll
    for (int j = 0; j < TN; ++j) {
      int n = bn + tn0 + j;
      if (n < V_DIM) C[(size_t)m * V_DIM + n] = (acc[i][j] + Bv[n]) / TEMP;
    }
  }
}

// ------------------ per-row top-k / top-p / softmax ------------------
// Reproduces the reference's DOUBLE-GATHER scatter:
//   out[i] = sorted2[perm[i]],  perm = argsort(-masked) (stable)
// which means: for q in [0,kc): out[rank_of_original_index_q] = P(q),
// everything else 0.

__device__ inline unsigned f2key(float f) {
  unsigned u = __float_as_uint(f);
  return (u & 0x80000000u) ? ~u : (u | 0x80000000u);
}
__device__ inline float key2f(unsigned u) {
  return __uint_as_float((u & 0x80000000u) ? (u & 0x7FFFFFFFu) : ~u);
}

#define CAP 256

__global__ __launch_bounds__(256) void select_kernel(float* __restrict__ C) {
  const int row = blockIdx.x;
  float* rowp = C + (size_t)row * V_DIM;
  const int tid = threadIdx.x;

  __shared__ unsigned hist[256];
  __shared__ unsigned s_sel;
  __shared__ int s_above;
  __shared__ float cval[CAP];   // sorted survivor values (desc)
  __shared__ int cidx[CAP];     // sorted survivor original indices
  __shared__ float pvals[CAP];  // exp(cval - m)
  __shared__ int s_cnt;
  __shared__ int s_kc;
  __shared__ float s_invZ;

  // ---- Phase 1: exact 50th-largest via 4-level radix select
  unsigned prefix = 0;
  int above = 0;
  for (int level = 0; level < 4; ++level) {
    const int shift = 24 - level * 8;
    hist[tid] = 0;
    __syncthreads();
    for (int v = tid; v < V_DIM; v += 256) {
      unsigned u = f2key(rowp[v]);
      bool ok = (level == 0) || ((u >> (shift + 8)) == (prefix >> (shift + 8)));
      if (ok) atomicAdd(&hist[(u >> shift) & 0xFFu], 1u);
    }
    __syncthreads();
    if (tid == 0) {
      int acc = above;
      int b = 255;
      for (; b > 0; --b) {
        int c = (int)hist[b];
        if (acc + c >= TOPK) break;
        acc += c;
      }
      s_sel = prefix | ((unsigned)b << shift);
      s_above = acc;
    }
    __syncthreads();
    prefix = s_sel;
    above = s_above;
    __syncthreads();
  }
  const float t = key2f(prefix);  // 50th largest (with multiplicity)

  // ---- Phase 2: collect survivors (logit >= t)
  if (tid == 0) s_cnt = 0;
  __syncthreads();
  for (int v = tid; v < V_DIM; v += 256) {
    float l = rowp[v];
    if (l >= t) {
      int p = atomicAdd(&s_cnt, 1);
      if (p < CAP) { cval[p] = l; cidx[p] = v; }
    }
  }
  __syncthreads();
  const int n = min(s_cnt, CAP);

  // ---- Phase 3+4: stable sort (val desc, idx asc) + softmax/cumsum/top-p
  if (tid == 0) {
    for (int i = 1; i < n; ++i) {
      float v = cval[i];
      int ix = cidx[i];
      int j = i - 1;
      while (j >= 0 && (cval[j] < v || (cval[j] == v && cidx[j] > ix))) {
        cval[j + 1] = cval[j];
        cidx[j + 1] = cidx[j];
        --j;
      }
      cval[j + 1] = v;
      cidx[j + 1] = ix;
    }
    float m = cval[0];
    float Z0 = 0.f;
    for (int i = 0; i < n; ++i) {
      pvals[i] = expf(cval[i] - m);
      Z0 += pvals[i];
    }
    float cum = 0.f;
    int kc = 0;
    float Z2 = 0.f;
    for (int i = 0; i < n; ++i) {
      cum += pvals[i] / Z0;
      if (cum > TOPP) break;
      kc = i + 1;
      Z2 += pvals[i];
    }
    s_kc = kc;
    s_invZ = (kc > 0) ? (1.f / Z2) : 0.f;
  }
  __syncthreads();
  const int kc = s_kc;
  const float invZ = s_invZ;

  // ---- Phase 5: zero the row, then scatter per the buggy double-gather:
  // out[rank(q)] = pvals[q]*invZ for q in [0, kc), where rank(q) is the
  // position of ORIGINAL INDEX q in the stable descending sort of the
  // top-k-masked row (non-survivors are -inf, stable-tie by index asc).
  for (int v = tid; v < V_DIM; v += 256) rowp[v] = 0.f;
  __syncthreads();
  for (int q = tid; q < kc; q += 256) {
    int r = -1;    // sorted position if q is a survivor
    int less = 0;  // survivors with original index < q
    for (int s = 0; s < n; ++s) {
      if (cidx[s] == q) r = s;
      if (cidx[s] < q) ++less;
    }
    int rank = (r >= 0) ? r : (n + q - less);
    rowp[rank] = pvals[q] * invZ;
  }
}

// ----------------------------- launcher ------------------------------
extern "C" void kernel_launch(void* const* d_in, const int* in_sizes, int n_in,
                              void* d_out, int out_size, void* d_ws, size_t ws_size,
                              hipStream_t stream) {
  const float* X = (const float*)d_in[0];   // (2,1024,512)
  const float* W = (const float*)d_in[1];   // (50257,512)
  const float* Bv = (const float*)d_in[2];  // (50257,)
  float* C = (float*)d_out;                 // (2,1024,50257)

  dim3 g1((V_DIM + BN - 1) / BN, M_TOT / BM);
  gemm_kernel<<<g1, 256, 0, stream>>>(X, W, Bv, C);
  select_kernel<<<M_TOT, 256, 0, stream>>>(C);
}

// Round 3
// 1241.547 us; speedup vs baseline: 2.9277x; 2.9277x over previous
//
#include <hip/hip_runtime.h>
#include <math.h>

// Problem constants
#define TEMP 0.7f
#define TOPK 50
#define TOPP 0.9f
#define M_TOT 2048      // B*S
#define K_DIM 512       // H
#define V_DIM 50257     // vocab
#define NPAD 50304      // 393*128 (N padded to tile)
#define KP 1536         // 3*K_DIM: [hi|hi|lo] x [hi|lo|hi]
#define BM 128
#define BN 128
#define BKE 64          // bf16 K-elements per LDS step
#define NSTEP (KP / BKE)

typedef short s16x8 __attribute__((ext_vector_type(8)));
typedef float f32x4 __attribute__((ext_vector_type(4)));

// mfma via inline asm (gfx950 unified VGPR/AGPR file; deps tracked via operands)
#define MFMA_16x16x32_BF16(acc, va, vb) \
  asm("v_mfma_f32_16x16x32_bf16 %0, %1, %2, %0" : "+v"(acc) : "v"(va), "v"(vb))

__device__ __forceinline__ unsigned short bf16_rn(float x) {
  unsigned u = __float_as_uint(x);
  unsigned r = u + 0x7FFFu + ((u >> 16) & 1u);
  return (unsigned short)(r >> 16);
}
__device__ __forceinline__ float bf16_to_f(unsigned short h) {
  return __uint_as_float(((unsigned)h) << 16);
}

// ---------------- conversion: X -> [hi|hi|lo], W -> [hi|lo|hi] ----------------
__global__ __launch_bounds__(256) void convx_kernel(const float* __restrict__ X,
                                                    unsigned short* __restrict__ Xp) {
  int idx = blockIdx.x * 256 + threadIdx.x;  // quad index
  const int total = M_TOT * (K_DIM / 4);
  if (idx >= total) return;
  int row = idx >> 7;  // K_DIM/4 = 128
  int q = idx & 127;
  const float4 v = reinterpret_cast<const float4*>(X)[idx];
  float vv[4] = {v.x, v.y, v.z, v.w};
  unsigned short hi[4], lo[4];
#pragma unroll
  for (int j = 0; j < 4; ++j) {
    hi[j] = bf16_rn(vv[j]);
    lo[j] = bf16_rn(vv[j] - bf16_to_f(hi[j]));
  }
  ushort4 h4 = make_ushort4(hi[0], hi[1], hi[2], hi[3]);
  ushort4 l4 = make_ushort4(lo[0], lo[1], lo[2], lo[3]);
  size_t base = (size_t)row * KP + q * 4;
  *reinterpret_cast<ushort4*>(Xp + base) = h4;
  *reinterpret_cast<ushort4*>(Xp + base + K_DIM) = h4;
  *reinterpret_cast<ushort4*>(Xp + base + 2 * K_DIM) = l4;
}

__global__ __launch_bounds__(256) void convw_kernel(const float* __restrict__ W,
                                                    unsigned short* __restrict__ Wp) {
  int idx = blockIdx.x * 256 + threadIdx.x;
  const int total = NPAD * (K_DIM / 4);
  if (idx >= total) return;
  int row = idx >> 7;
  int q = idx & 127;
  float4 v = make_float4(0.f, 0.f, 0.f, 0.f);
  if (row < V_DIM) v = reinterpret_cast<const float4*>(W)[(size_t)row * 128 + q];
  float vv[4] = {v.x, v.y, v.z, v.w};
  unsigned short hi[4], lo[4];
#pragma unroll
  for (int j = 0; j < 4; ++j) {
    hi[j] = bf16_rn(vv[j]);
    lo[j] = bf16_rn(vv[j] - bf16_to_f(hi[j]));
  }
  ushort4 h4 = make_ushort4(hi[0], hi[1], hi[2], hi[3]);
  ushort4 l4 = make_ushort4(lo[0], lo[1], lo[2], lo[3]);
  size_t base = (size_t)row * KP + q * 4;
  *reinterpret_cast<ushort4*>(Wp + base) = h4;
  *reinterpret_cast<ushort4*>(Wp + base + K_DIM) = l4;
  *reinterpret_cast<ushort4*>(Wp + base + 2 * K_DIM) = h4;
}

// ---------------- MFMA GEMM: C[m][n] = (A'.B'^T + b[n]) / TEMP ----------------
// 128x128 tile, 4 waves (2x2), per-wave 64x64 = 4x4 frags of 16x16x32.
// LDS: linear dest for global_load_lds, inverse-swizzled global source,
// XOR-swizzled ds_read (byte ^= (row&7)<<4) -> 2-way-max bank aliasing.
__global__ __launch_bounds__(256) void mfma_gemm_kernel(
    const unsigned short* __restrict__ Ap, const unsigned short* __restrict__ Bp,
    const float* __restrict__ Bv, float* __restrict__ C) {
  __shared__ __align__(16) unsigned char lds[32768];  // As [0,16K), Bs [16K,32K)
  const int tid = threadIdx.x;
  const int w = tid >> 6, lane = tid & 63;
  const int bm = blockIdx.x * BM;
  const int bn = blockIdx.y * BN;
  const int wr = w >> 1, wc = w & 1;

  f32x4 acc[4][4] = {};

  for (int step = 0; step < NSTEP; ++step) {
    const int k0 = step * BKE;
    // stage A,B tiles: 16KB each, wave w covers rounds w*4..w*4+3 (1024B each)
#pragma unroll
    for (int q = 0; q < 4; ++q) {
      int pp = ((w * 4 + q) << 10) + (lane << 4);  // linear LDS byte offset
      int row = pp >> 7;                           // tile row (128B rows)
      int cb = (pp & 127) ^ ((row & 7) << 4);      // logical column byte
      const unsigned short* ga = Ap + (size_t)(bm + row) * KP + k0 + (cb >> 1);
      __builtin_amdgcn_global_load_lds(
          (const __attribute__((address_space(1))) unsigned int*)ga,
          (__attribute__((address_space(3))) unsigned int*)(lds + pp), 16, 0, 0);
      const unsigned short* gb = Bp + (size_t)(bn + row) * KP + k0 + (cb >> 1);
      __builtin_amdgcn_global_load_lds(
          (const __attribute__((address_space(1))) unsigned int*)gb,
          (__attribute__((address_space(3))) unsigned int*)(lds + 16384 + pp), 16, 0, 0);
    }
    __syncthreads();
#pragma unroll
    for (int kk = 0; kk < 2; ++kk) {
      const int kbyte = kk * 64 + ((lane >> 4) << 4);
      s16x8 a[4], b[4];
#pragma unroll
      for (int i = 0; i < 4; ++i) {
        int row = (wr << 6) + (i << 4) + (lane & 15);
        int byte = (row << 7) + (kbyte ^ ((row & 7) << 4));
        a[i] = *reinterpret_cast<const s16x8*>(lds + byte);
      }
#pragma unroll
      for (int j = 0; j < 4; ++j) {
        int row = (wc << 6) + (j << 4) + (lane & 15);
        int byte = (row << 7) + (kbyte ^ ((row & 7) << 4));
        b[j] = *reinterpret_cast<const s16x8*>(lds + 16384 + byte);
      }
#pragma unroll
      for (int i = 0; i < 4; ++i)
#pragma unroll
        for (int j = 0; j < 4; ++j) MFMA_16x16x32_BF16(acc[i][j], a[i], b[j]);
    }
    __syncthreads();
  }

  // epilogue: D lane layout row=(lane>>4)*4+r, col=lane&15
#pragma unroll
  for (int i = 0; i < 4; ++i) {
#pragma unroll
    for (int j = 0; j < 4; ++j) {
      int n = bn + (wc << 6) + (j << 4) + (lane & 15);
      if (n < V_DIM) {
        float bv = Bv[n];
#pragma unroll
        for (int r = 0; r < 4; ++r) {
          int m = bm + (wr << 6) + (i << 4) + ((lane >> 4) << 2) + r;
          C[(size_t)m * V_DIM + n] = (acc[i][j][r] + bv) / TEMP;
        }
      }
    }
  }
}

// ---------------- fallback f32 GEMM (used only if ws too small) ----------------
#define FBM 64
#define FBN 64
#define FBK 32
__global__ __launch_bounds__(256) void gemm_kernel(
    const float* __restrict__ X, const float* __restrict__ W,
    const float* __restrict__ Bv, float* __restrict__ C) {
  __shared__ float As[FBM][FBK + 1];
  __shared__ float Bs[FBN][FBK + 1];
  const int bm = blockIdx.y * FBM;
  const int bn = blockIdx.x * FBN;
  const int tid = threadIdx.x;
  const int tm0 = (tid / 16) * 4;
  const int tn0 = (tid % 16) * 4;
  float acc[4][4] = {};
  const int lk = tid % FBK;
  const int lr = tid / FBK;
  for (int k0 = 0; k0 < K_DIM; k0 += FBK) {
#pragma unroll
    for (int r = 0; r < FBM; r += 8)
      As[lr + r][lk] = X[(size_t)(bm + lr + r) * K_DIM + k0 + lk];
#pragma unroll
    for (int r = 0; r < FBN; r += 8) {
      int n = bn + lr + r;
      Bs[lr + r][lk] = (n < V_DIM) ? W[(size_t)n * K_DIM + k0 + lk] : 0.f;
    }
    __syncthreads();
#pragma unroll
    for (int k = 0; k < FBK; ++k) {
      float a[4], bb[4];
#pragma unroll
      for (int i = 0; i < 4; ++i) a[i] = As[tm0 + i][k];
#pragma unroll
      for (int j = 0; j < 4; ++j) bb[j] = Bs[tn0 + j][k];
#pragma unroll
      for (int i = 0; i < 4; ++i)
#pragma unroll
        for (int j = 0; j < 4; ++j) acc[i][j] += a[i] * bb[j];
    }
    __syncthreads();
  }
#pragma unroll
  for (int i = 0; i < 4; ++i) {
    int m = bm + tm0 + i;
#pragma unroll
    for (int j = 0; j < 4; ++j) {
      int n = bn + tn0 + j;
      if (n < V_DIM) C[(size_t)m * V_DIM + n] = (acc[i][j] + Bv[n]) / TEMP;
    }
  }
}

// ------------------ per-row top-k / top-p / softmax ------------------
__device__ inline unsigned f2key(float f) {
  unsigned u = __float_as_uint(f);
  return (u & 0x80000000u) ? ~u : (u | 0x80000000u);
}
__device__ inline float key2f(unsigned u) {
  return __uint_as_float((u & 0x80000000u) ? (u & 0x7FFFFFFFu) : ~u);
}

#define CAP 256

__global__ __launch_bounds__(256) void select_kernel(float* __restrict__ C) {
  const int row = blockIdx.x;
  float* rowp = C + (size_t)row * V_DIM;
  const int tid = threadIdx.x;

  __shared__ unsigned hist[256];
  __shared__ unsigned s_sel;
  __shared__ int s_above;
  __shared__ float cval[CAP];
  __shared__ int cidx[CAP];
  __shared__ float pvals[CAP];
  __shared__ int s_cnt;
  __shared__ int s_kc;
  __shared__ float s_invZ;

  // Phase 1: exact 50th-largest via 4-level radix select
  unsigned prefix = 0;
  int above = 0;
  for (int level = 0; level < 4; ++level) {
    const int shift = 24 - level * 8;
    hist[tid] = 0;
    __syncthreads();
    for (int v = tid; v < V_DIM; v += 256) {
      unsigned u = f2key(rowp[v]);
      bool ok = (level == 0) || ((u >> (shift + 8)) == (prefix >> (shift + 8)));
      if (ok) atomicAdd(&hist[(u >> shift) & 0xFFu], 1u);
    }
    __syncthreads();
    if (tid == 0) {
      int acc = above;
      int b = 255;
      for (; b > 0; --b) {
        int c = (int)hist[b];
        if (acc + c >= TOPK) break;
        acc += c;
      }
      s_sel = prefix | ((unsigned)b << shift);
      s_above = acc;
    }
    __syncthreads();
    prefix = s_sel;
    above = s_above;
    __syncthreads();
  }
  const float t = key2f(prefix);

  // Phase 2: collect survivors (logit >= t)
  if (tid == 0) s_cnt = 0;
  __syncthreads();
  for (int v = tid; v < V_DIM; v += 256) {
    float l = rowp[v];
    if (l >= t) {
      int p = atomicAdd(&s_cnt, 1);
      if (p < CAP) { cval[p] = l; cidx[p] = v; }
    }
  }
  __syncthreads();
  const int n = min(s_cnt, CAP);

  // Phase 3+4: stable sort (desc, idx asc) + softmax/cumsum/top-p
  if (tid == 0) {
    for (int i = 1; i < n; ++i) {
      float v = cval[i];
      int ix = cidx[i];
      int j = i - 1;
      while (j >= 0 && (cval[j] < v || (cval[j] == v && cidx[j] > ix))) {
        cval[j + 1] = cval[j];
        cidx[j + 1] = cidx[j];
        --j;
      }
      cval[j + 1] = v;
      cidx[j + 1] = ix;
    }
    float m = cval[0];
    float Z0 = 0.f;
    for (int i = 0; i < n; ++i) {
      pvals[i] = expf(cval[i] - m);
      Z0 += pvals[i];
    }
    float cum = 0.f;
    int kc = 0;
    float Z2 = 0.f;
    for (int i = 0; i < n; ++i) {
      cum += pvals[i] / Z0;
      if (cum > TOPP) break;
      kc = i + 1;
      Z2 += pvals[i];
    }
    s_kc = kc;
    s_invZ = (kc > 0) ? (1.f / Z2) : 0.f;
  }
  __syncthreads();
  const int kc = s_kc;
  const float invZ = s_invZ;

  // Phase 5: zero row, scatter per the reference's double-gather semantics
  for (int v = tid; v < V_DIM; v += 256) rowp[v] = 0.f;
  __syncthreads();
  for (int q = tid; q < kc; q += 256) {
    int r = -1;
    int less = 0;
    for (int s = 0; s < n; ++s) {
      if (cidx[s] == q) r = s;
      if (cidx[s] < q) ++less;
    }
    int rank = (r >= 0) ? r : (n + q - less);
    rowp[rank] = pvals[q] * invZ;
  }
}

// ----------------------------- launcher ------------------------------
extern "C" void kernel_launch(void* const* d_in, const int* in_sizes, int n_in,
                              void* d_out, int out_size, void* d_ws, size_t ws_size,
                              hipStream_t stream) {
  const float* X = (const float*)d_in[0];   // (2,1024,512)
  const float* W = (const float*)d_in[1];   // (50257,512)
  const float* Bv = (const float*)d_in[2];  // (50257,)
  float* C = (float*)d_out;                 // (2,1024,50257)

  const size_t xp_elems = (size_t)M_TOT * KP;
  const size_t wp_elems = (size_t)NPAD * KP;
  const size_t need = (xp_elems + wp_elems) * sizeof(unsigned short);

  if (ws_size >= need) {
    unsigned short* Xp = (unsigned short*)d_ws;
    unsigned short* Wp = Xp + xp_elems;
    convx_kernel<<<(M_TOT * (K_DIM / 4) + 255) / 256, 256, 0, stream>>>(X, Xp);
    convw_kernel<<<(NPAD * (K_DIM / 4) + 255) / 256, 256, 0, stream>>>(W, Wp);
    dim3 g(M_TOT / BM, NPAD / BN);  // M fastest: consecutive blocks share B panel
    mfma_gemm_kernel<<<g, 256, 0, stream>>>(Xp, Wp, Bv, C);
  } else {
    dim3 g1((V_DIM + FBN - 1) / FBN, M_TOT / FBM);
    gemm_kernel<<<g1, 256, 0, stream>>>(X, W, Bv, C);
  }
  select_kernel<<<M_TOT, 256, 0, stream>>>(C);
}

// Round 4
// 828.552 us; speedup vs baseline: 4.3870x; 1.4985x over previous
//
#include <hip/hip_runtime.h>
#include <math.h>

// Problem constants
#define TEMP 0.7f
#define TOPK 50
#define TOPP 0.9f
#define M_TOT 2048      // B*S
#define K_DIM 512       // H
#define V_DIM 50257     // vocab
#define NPAD 50304      // 393*128 (N padded to tile)
#define KP 1536         // 3*K_DIM: [hi|hi|lo] x [hi|lo|hi]
#define BM 128
#define BN 128
#define BKE 64          // bf16 K-elements per LDS step
#define NSTEP (KP / BKE)

typedef short s16x8 __attribute__((ext_vector_type(8)));
typedef float f32x4 __attribute__((ext_vector_type(4)));

#define MFMA_16x16x32_BF16(acc, va, vb) \
  asm("v_mfma_f32_16x16x32_bf16 %0, %1, %2, %0" : "+v"(acc) : "v"(va), "v"(vb))

__device__ __forceinline__ unsigned short bf16_rn(float x) {
  unsigned u = __float_as_uint(x);
  unsigned r = u + 0x7FFFu + ((u >> 16) & 1u);
  return (unsigned short)(r >> 16);
}
__device__ __forceinline__ float bf16_to_f(unsigned short h) {
  return __uint_as_float(((unsigned)h) << 16);
}

// ---------------- conversion: X -> [hi|hi|lo], W -> [hi|lo|hi] ----------------
__global__ __launch_bounds__(256) void convx_kernel(const float* __restrict__ X,
                                                    unsigned short* __restrict__ Xp) {
  int idx = blockIdx.x * 256 + threadIdx.x;  // quad index
  const int total = M_TOT * (K_DIM / 4);
  if (idx >= total) return;
  int row = idx >> 7;
  int q = idx & 127;
  const float4 v = reinterpret_cast<const float4*>(X)[idx];
  float vv[4] = {v.x, v.y, v.z, v.w};
  unsigned short hi[4], lo[4];
#pragma unroll
  for (int j = 0; j < 4; ++j) {
    hi[j] = bf16_rn(vv[j]);
    lo[j] = bf16_rn(vv[j] - bf16_to_f(hi[j]));
  }
  ushort4 h4 = make_ushort4(hi[0], hi[1], hi[2], hi[3]);
  ushort4 l4 = make_ushort4(lo[0], lo[1], lo[2], lo[3]);
  size_t base = (size_t)row * KP + q * 4;
  *reinterpret_cast<ushort4*>(Xp + base) = h4;
  *reinterpret_cast<ushort4*>(Xp + base + K_DIM) = h4;
  *reinterpret_cast<ushort4*>(Xp + base + 2 * K_DIM) = l4;
}

__global__ __launch_bounds__(256) void convw_kernel(const float* __restrict__ W,
                                                    unsigned short* __restrict__ Wp) {
  int idx = blockIdx.x * 256 + threadIdx.x;
  const int total = NPAD * (K_DIM / 4);
  if (idx >= total) return;
  int row = idx >> 7;
  int q = idx & 127;
  float4 v = make_float4(0.f, 0.f, 0.f, 0.f);
  if (row < V_DIM) v = reinterpret_cast<const float4*>(W)[(size_t)row * 128 + q];
  float vv[4] = {v.x, v.y, v.z, v.w};
  unsigned short hi[4], lo[4];
#pragma unroll
  for (int j = 0; j < 4; ++j) {
    hi[j] = bf16_rn(vv[j]);
    lo[j] = bf16_rn(vv[j] - bf16_to_f(hi[j]));
  }
  ushort4 h4 = make_ushort4(hi[0], hi[1], hi[2], hi[3]);
  ushort4 l4 = make_ushort4(lo[0], lo[1], lo[2], lo[3]);
  size_t base = (size_t)row * KP + q * 4;
  *reinterpret_cast<ushort4*>(Wp + base) = h4;
  *reinterpret_cast<ushort4*>(Wp + base + K_DIM) = l4;
  *reinterpret_cast<ushort4*>(Wp + base + 2 * K_DIM) = h4;
}

// ---------------- MFMA GEMM: C[m][n] = (A'.B'^T + b[n]) / TEMP ----------------
__global__ __launch_bounds__(256) void mfma_gemm_kernel(
    const unsigned short* __restrict__ Ap, const unsigned short* __restrict__ Bp,
    const float* __restrict__ Bv, float* __restrict__ C) {
  __shared__ __align__(16) unsigned char lds[32768];
  const int tid = threadIdx.x;
  const int w = tid >> 6, lane = tid & 63;
  const int bm = blockIdx.x * BM;
  const int bn = blockIdx.y * BN;
  const int wr = w >> 1, wc = w & 1;

  f32x4 acc[4][4] = {};

  for (int step = 0; step < NSTEP; ++step) {
    const int k0 = step * BKE;
#pragma unroll
    for (int q = 0; q < 4; ++q) {
      int pp = ((w * 4 + q) << 10) + (lane << 4);
      int row = pp >> 7;
      int cb = (pp & 127) ^ ((row & 7) << 4);
      const unsigned short* ga = Ap + (size_t)(bm + row) * KP + k0 + (cb >> 1);
      __builtin_amdgcn_global_load_lds(
          (const __attribute__((address_space(1))) unsigned int*)ga,
          (__attribute__((address_space(3))) unsigned int*)(lds + pp), 16, 0, 0);
      const unsigned short* gb = Bp + (size_t)(bn + row) * KP + k0 + (cb >> 1);
      __builtin_amdgcn_global_load_lds(
          (const __attribute__((address_space(1))) unsigned int*)gb,
          (__attribute__((address_space(3))) unsigned int*)(lds + 16384 + pp), 16, 0, 0);
    }
    __syncthreads();
#pragma unroll
    for (int kk = 0; kk < 2; ++kk) {
      const int kbyte = kk * 64 + ((lane >> 4) << 4);
      s16x8 a[4], b[4];
#pragma unroll
      for (int i = 0; i < 4; ++i) {
        int row = (wr << 6) + (i << 4) + (lane & 15);
        int byte = (row << 7) + (kbyte ^ ((row & 7) << 4));
        a[i] = *reinterpret_cast<const s16x8*>(lds + byte);
      }
#pragma unroll
      for (int j = 0; j < 4; ++j) {
        int row = (wc << 6) + (j << 4) + (lane & 15);
        int byte = (row << 7) + (kbyte ^ ((row & 7) << 4));
        b[j] = *reinterpret_cast<const s16x8*>(lds + 16384 + byte);
      }
#pragma unroll
      for (int i = 0; i < 4; ++i)
#pragma unroll
        for (int j = 0; j < 4; ++j) MFMA_16x16x32_BF16(acc[i][j], a[i], b[j]);
    }
    __syncthreads();
  }

#pragma unroll
  for (int i = 0; i < 4; ++i) {
#pragma unroll
    for (int j = 0; j < 4; ++j) {
      int n = bn + (wc << 6) + (j << 4) + (lane & 15);
      if (n < V_DIM) {
        float bv = Bv[n];
#pragma unroll
        for (int r = 0; r < 4; ++r) {
          int m = bm + (wr << 6) + (i << 4) + ((lane >> 4) << 2) + r;
          C[(size_t)m * V_DIM + n] = (acc[i][j][r] + bv) / TEMP;
        }
      }
    }
  }
}

// ------------------ per-row top-k / top-p / softmax (2-pass) ------------------
__device__ inline unsigned f2key(float f) {
  unsigned u = __float_as_uint(f);
  return (u & 0x80000000u) ? ~u : (u | 0x80000000u);
}

#define CAP 1024   // candidate capacity (bin superset)
#define SCAP 256   // survivor capacity

__global__ __launch_bounds__(256) void select_kernel(float* __restrict__ C) {
  const int row = blockIdx.x;
  float* rowp = C + (size_t)row * V_DIM;
  const int tid = threadIdx.x;

  __shared__ unsigned hist[2048];
  __shared__ float cval[CAP];
  __shared__ int cidx[CAP];
  __shared__ float sval[SCAP];
  __shared__ int sidx[SCAP];
  __shared__ float pvals[SCAP];
  __shared__ int s_cnt, s_bin, s_nsurv, s_kc;
  __shared__ float s_invZ;

  // ---- Pass 1: 2048-bin histogram of key>>21 (sign+exp+3 mantissa bits)
  for (int i = tid; i < 2048; i += 256) hist[i] = 0;
  if (tid == 0) { s_cnt = 0; s_nsurv = 0; }
  __syncthreads();
  const int NQ = V_DIM >> 2;  // 12564 full quads; element 50256 is the tail
  for (int q = tid; q < NQ; q += 256) {
    float4 v = reinterpret_cast<const float4*>(rowp)[q];
    atomicAdd(&hist[f2key(v.x) >> 21], 1u);
    atomicAdd(&hist[f2key(v.y) >> 21], 1u);
    atomicAdd(&hist[f2key(v.z) >> 21], 1u);
    atomicAdd(&hist[f2key(v.w) >> 21], 1u);
  }
  if (tid == 0) atomicAdd(&hist[f2key(rowp[V_DIM - 1]) >> 21], 1u);
  __syncthreads();
  if (tid == 0) {
    int acc = 0;
    int b = 2047;
    for (; b > 0; --b) {
      acc += (int)hist[b];
      if (acc >= TOPK) break;
    }
    s_bin = b;  // 50th-largest lives in bin b; candidates = all with bin >= b
  }
  __syncthreads();
  const unsigned bfloor = (unsigned)s_bin;

  // ---- Pass 2: collect candidates AND zero the row in the same sweep
  const float4 z4 = make_float4(0.f, 0.f, 0.f, 0.f);
  for (int q = tid; q < NQ; q += 256) {
    float4 v = reinterpret_cast<const float4*>(rowp)[q];
    float vv[4] = {v.x, v.y, v.z, v.w};
#pragma unroll
    for (int j = 0; j < 4; ++j) {
      if ((f2key(vv[j]) >> 21) >= bfloor) {
        int p = atomicAdd(&s_cnt, 1);
        if (p < CAP) { cval[p] = vv[j]; cidx[p] = q * 4 + j; }
      }
    }
    reinterpret_cast<float4*>(rowp)[q] = z4;
  }
  if (tid == 0) {
    float l = rowp[V_DIM - 1];
    if ((f2key(l) >> 21) >= bfloor) {
      int p = atomicAdd(&s_cnt, 1);
      if (p < CAP) { cval[p] = l; cidx[p] = V_DIM - 1; }
    }
    rowp[V_DIM - 1] = 0.f;
  }
  __syncthreads();
  const int n = min(s_cnt, CAP);  // n >= TOPK by construction

  // ---- parallel stable rank (val desc, idx asc): distinct ranks
  for (int i = tid; i < n; i += 256) {
    float vi = cval[i];
    int xi = cidx[i];
    int r = 0;
    for (int j = 0; j < n; ++j) {
      float vj = cval[j];
      if (vj > vi || (vj == vi && cidx[j] < xi)) ++r;
    }
    if (r < SCAP) { sval[r] = vi; sidx[r] = xi; }
  }
  __syncthreads();

  // ---- exact top-k threshold + survivor count (float compares, like ref)
  const float t = sval[TOPK - 1];
  for (int i = tid; i < n; i += 256)
    if (cval[i] >= t) atomicAdd(&s_nsurv, 1);
  __syncthreads();
  const int nsurv = min(s_nsurv, SCAP);  // survivors = sorted[0..nsurv)

  // ---- softmax numerators over survivors
  const float m = sval[0];
  for (int i = tid; i < nsurv; i += 256) pvals[i] = expf(sval[i] - m);
  __syncthreads();
  if (tid == 0) {
    float Z0 = 0.f;
    for (int i = 0; i < nsurv; ++i) Z0 += pvals[i];
    float cum = 0.f;
    int kc = 0;
    float Z2 = 0.f;
    for (int i = 0; i < nsurv; ++i) {
      cum += pvals[i] / Z0;
      if (cum > TOPP) break;
      kc = i + 1;
      Z2 += pvals[i];
    }
    s_kc = kc;
    s_invZ = (kc > 0) ? (1.f / Z2) : 0.f;
  }
  __syncthreads();
  const int kc = s_kc;
  const float invZ = s_invZ;

  // ---- scatter per the reference's double-gather: out[rank(q)] = P(q)
  for (int q = tid; q < kc; q += 256) {
    int r = -1, less = 0;
    for (int s = 0; s < nsurv; ++s) {
      if (sidx[s] == q) r = s;
      if (sidx[s] < q) ++less;
    }
    int rank = (r >= 0) ? r : (nsurv + q - less);
    rowp[rank] = pvals[q] * invZ;
  }
}

// ----------------------------- launcher ------------------------------
extern "C" void kernel_launch(void* const* d_in, const int* in_sizes, int n_in,
                              void* d_out, int out_size, void* d_ws, size_t ws_size,
                              hipStream_t stream) {
  const float* X = (const float*)d_in[0];   // (2,1024,512)
  const float* W = (const float*)d_in[1];   // (50257,512)
  const float* Bv = (const float*)d_in[2];  // (50257,)
  float* C = (float*)d_out;                 // (2,1024,50257)

  unsigned short* Xp = (unsigned short*)d_ws;
  unsigned short* Wp = Xp + (size_t)M_TOT * KP;

  convx_kernel<<<(M_TOT * (K_DIM / 4) + 255) / 256, 256, 0, stream>>>(X, Xp);
  convw_kernel<<<(NPAD * (K_DIM / 4) + 255) / 256, 256, 0, stream>>>(W, Wp);
  dim3 g(M_TOT / BM, NPAD / BN);  // M fastest: consecutive blocks share B panel
  mfma_gemm_kernel<<<g, 256, 0, stream>>>(Xp, Wp, Bv, C);
  select_kernel<<<M_TOT, 256, 0, stream>>>(C);
}

// Round 5
// 739.578 us; speedup vs baseline: 4.9148x; 1.1203x over previous
//
#include <hip/hip_runtime.h>
#include <math.h>

// Problem constants
#define TEMP 0.7f
#define TOPK 50
#define TOPP 0.9f
#define M_TOT 2048      // B*S
#define K_DIM 512       // H
#define V_DIM 50257     // vocab
#define NPAD 50304      // 393*128
#define KP 1536         // 3*K_DIM: [hi|hi|lo] x [hi|lo|hi]
#define BM 128
#define BN 128
#define BKE 64
#define NSTEP (KP / BKE)
#define NBN (NPAD / BN)  // 393 N-tiles
#define NBM (M_TOT / BM) // 16 M-tiles

typedef short s16x8 __attribute__((ext_vector_type(8)));
typedef float f32x4 __attribute__((ext_vector_type(4)));

#define MFMA_16x16x32_BF16(acc, va, vb) \
  asm("v_mfma_f32_16x16x32_bf16 %0, %1, %2, %0" : "+v"(acc) : "v"(va), "v"(vb))

__device__ __forceinline__ unsigned short bf16_rn(float x) {
  unsigned u = __float_as_uint(x);
  unsigned r = u + 0x7FFFu + ((u >> 16) & 1u);
  return (unsigned short)(r >> 16);
}
__device__ __forceinline__ float bf16_to_f(unsigned short h) {
  return __uint_as_float(((unsigned)h) << 16);
}
__device__ __forceinline__ unsigned f2key(float f) {
  unsigned u = __float_as_uint(f);
  return (u & 0x80000000u) ? ~u : (u | 0x80000000u);
}

// ---------------- conversion: X -> [hi|hi|lo], W -> [hi|lo|hi] ----------------
__global__ __launch_bounds__(256) void convx_kernel(const float* __restrict__ X,
                                                    unsigned short* __restrict__ Xp) {
  int idx = blockIdx.x * 256 + threadIdx.x;
  const int total = M_TOT * (K_DIM / 4);
  if (idx >= total) return;
  int row = idx >> 7;
  int q = idx & 127;
  const float4 v = reinterpret_cast<const float4*>(X)[idx];
  float vv[4] = {v.x, v.y, v.z, v.w};
  unsigned short hi[4], lo[4];
#pragma unroll
  for (int j = 0; j < 4; ++j) {
    hi[j] = bf16_rn(vv[j]);
    lo[j] = bf16_rn(vv[j] - bf16_to_f(hi[j]));
  }
  ushort4 h4 = make_ushort4(hi[0], hi[1], hi[2], hi[3]);
  ushort4 l4 = make_ushort4(lo[0], lo[1], lo[2], lo[3]);
  size_t base = (size_t)row * KP + q * 4;
  *reinterpret_cast<ushort4*>(Xp + base) = h4;
  *reinterpret_cast<ushort4*>(Xp + base + K_DIM) = h4;
  *reinterpret_cast<ushort4*>(Xp + base + 2 * K_DIM) = l4;
}

__global__ __launch_bounds__(256) void convw_kernel(const float* __restrict__ W,
                                                    unsigned short* __restrict__ Wp) {
  int idx = blockIdx.x * 256 + threadIdx.x;
  const int total = NPAD * (K_DIM / 4);
  if (idx >= total) return;
  int row = idx >> 7;
  int q = idx & 127;
  float4 v = make_float4(0.f, 0.f, 0.f, 0.f);
  if (row < V_DIM) v = reinterpret_cast<const float4*>(W)[(size_t)row * 128 + q];
  float vv[4] = {v.x, v.y, v.z, v.w};
  unsigned short hi[4], lo[4];
#pragma unroll
  for (int j = 0; j < 4; ++j) {
    hi[j] = bf16_rn(vv[j]);
    lo[j] = bf16_rn(vv[j] - bf16_to_f(hi[j]));
  }
  ushort4 h4 = make_ushort4(hi[0], hi[1], hi[2], hi[3]);
  ushort4 l4 = make_ushort4(lo[0], lo[1], lo[2], lo[3]);
  size_t base = (size_t)row * KP + q * 4;
  *reinterpret_cast<ushort4*>(Wp + base) = h4;
  *reinterpret_cast<ushort4*>(Wp + base + K_DIM) = l4;
  *reinterpret_cast<ushort4*>(Wp + base + 2 * K_DIM) = h4;
}

// ---------------- MFMA GEMM + per-(row, N-tile) max epilogue ----------------
// 1D grid of 6288 tiles, bijective chunked XCD swizzle (m204): each XCD gets
// a contiguous tile range so the 16 M-tiles sharing a B-panel hit one L2.
__global__ __launch_bounds__(256) void mfma_gemm_kernel(
    const unsigned short* __restrict__ Ap, const unsigned short* __restrict__ Bp,
    const float* __restrict__ Bv, float* __restrict__ C,
    unsigned* __restrict__ Tmax) {
  __shared__ __align__(16) unsigned char lds[32768];
  __shared__ unsigned umax[BM];
  const int tid = threadIdx.x;
  const int w = tid >> 6, lane = tid & 63;

  // XCD swizzle: nwg = 6288 = 8*786 exactly
  const int nwg = NBM * NBN;
  const int qch = nwg >> 3;
  const int tile = (blockIdx.x & 7) * qch + (blockIdx.x >> 3);
  const int bm = (tile & (NBM - 1)) * BM;
  const int bni = tile / NBM;
  const int bn = bni * BN;
  const int wr = w >> 1, wc = w & 1;

  f32x4 acc[4][4] = {};

  for (int step = 0; step < NSTEP; ++step) {
    const int k0 = step * BKE;
#pragma unroll
    for (int q = 0; q < 4; ++q) {
      int pp = ((w * 4 + q) << 10) + (lane << 4);
      int row = pp >> 7;
      int cb = (pp & 127) ^ ((row & 7) << 4);
      const unsigned short* ga = Ap + (size_t)(bm + row) * KP + k0 + (cb >> 1);
      __builtin_amdgcn_global_load_lds(
          (const __attribute__((address_space(1))) unsigned int*)ga,
          (__attribute__((address_space(3))) unsigned int*)(lds + pp), 16, 0, 0);
      const unsigned short* gb = Bp + (size_t)(bn + row) * KP + k0 + (cb >> 1);
      __builtin_amdgcn_global_load_lds(
          (const __attribute__((address_space(1))) unsigned int*)gb,
          (__attribute__((address_space(3))) unsigned int*)(lds + 16384 + pp), 16, 0, 0);
    }
    __syncthreads();
#pragma unroll
    for (int kk = 0; kk < 2; ++kk) {
      const int kbyte = kk * 64 + ((lane >> 4) << 4);
      s16x8 a[4], b[4];
#pragma unroll
      for (int i = 0; i < 4; ++i) {
        int row = (wr << 6) + (i << 4) + (lane & 15);
        int byte = (row << 7) + (kbyte ^ ((row & 7) << 4));
        a[i] = *reinterpret_cast<const s16x8*>(lds + byte);
      }
#pragma unroll
      for (int j = 0; j < 4; ++j) {
        int row = (wc << 6) + (j << 4) + (lane & 15);
        int byte = (row << 7) + (kbyte ^ ((row & 7) << 4));
        b[j] = *reinterpret_cast<const s16x8*>(lds + 16384 + byte);
      }
#pragma unroll
      for (int i = 0; i < 4; ++i)
#pragma unroll
        for (int j = 0; j < 4; ++j) MFMA_16x16x32_BF16(acc[i][j], a[i], b[j]);
    }
    __syncthreads();
  }

  if (tid < BM) umax[tid] = 0;  // key(-inf floor): all finite keys exceed 0
  __syncthreads();

  // epilogue: store C and track per-row max of final logits
  float mx[4][4];  // [i][r] per-lane row maxima over j
#pragma unroll
  for (int i = 0; i < 4; ++i)
#pragma unroll
    for (int r = 0; r < 4; ++r) mx[i][r] = -INFINITY;

#pragma unroll
  for (int i = 0; i < 4; ++i) {
#pragma unroll
    for (int j = 0; j < 4; ++j) {
      int n = bn + (wc << 6) + (j << 4) + (lane & 15);
      if (n < V_DIM) {
        float bv = Bv[n];
#pragma unroll
        for (int r = 0; r < 4; ++r) {
          int m = bm + (wr << 6) + (i << 4) + ((lane >> 4) << 2) + r;
          float val = (acc[i][j][r] + bv) / TEMP;
          C[(size_t)m * V_DIM + n] = val;
          mx[i][r] = fmaxf(mx[i][r], val);
        }
      }
    }
  }
  // reduce across the 16 lanes (lane&15) sharing each row, then combine waves
#pragma unroll
  for (int i = 0; i < 4; ++i) {
#pragma unroll
    for (int r = 0; r < 4; ++r) {
      float v = mx[i][r];
      v = fmaxf(v, __shfl_xor(v, 1));
      v = fmaxf(v, __shfl_xor(v, 2));
      v = fmaxf(v, __shfl_xor(v, 4));
      v = fmaxf(v, __shfl_xor(v, 8));
      if ((lane & 15) == 0)
        atomicMax(&umax[(wr << 6) + (i << 4) + ((lane >> 4) << 2) + r], f2key(v));
    }
  }
  __syncthreads();
  if (tid < BM) Tmax[(size_t)(bm + tid) * NBN + bni] = umax[tid];
}

// ------------- per-row select: 1 sweep using tile-max lower bound -------------
#define CAP 1024
#define SCAP 256

__global__ __launch_bounds__(256) void select_kernel(float* __restrict__ C,
                                                     const unsigned* __restrict__ Tmax) {
  const int row = blockIdx.x;
  float* rowp = C + (size_t)row * V_DIM;
  const int tid = threadIdx.x;

  __shared__ unsigned tk[NBN];
  __shared__ unsigned s_t50;
  __shared__ float cval[CAP];
  __shared__ int cidx[CAP];
  __shared__ float sval[SCAP];
  __shared__ int sidx[SCAP];
  __shared__ float pvals[SCAP];
  __shared__ int s_cnt, s_nsurv, s_kc;
  __shared__ float s_invZ;

  // t50 = 50th-largest tile max (key space). True top-k threshold tau >= t50,
  // since the 50 largest tile-maxima are 50 distinct row values >= t50.
  for (int i = tid; i < NBN; i += 256) tk[i] = Tmax[(size_t)row * NBN + i];
  if (tid == 0) { s_cnt = 0; s_nsurv = 0; }
  __syncthreads();
  for (int i = tid; i < NBN; i += 256) {
    unsigned ki = tk[i];
    int r = 0;
    for (int j = 0; j < NBN; ++j) {
      unsigned kj = tk[j];
      r += (kj > ki) || (kj == ki && j < i);
    }
    if (r == TOPK - 1) s_t50 = ki;
  }
  __syncthreads();
  const unsigned t50 = s_t50;

  // single sweep: collect candidates (key >= t50) and zero the row
  const float4 z4 = make_float4(0.f, 0.f, 0.f, 0.f);
  const int NQ = V_DIM >> 2;
  for (int q = tid; q < NQ; q += 256) {
    float4 v = reinterpret_cast<const float4*>(rowp)[q];
    float vv[4] = {v.x, v.y, v.z, v.w};
#pragma unroll
    for (int j = 0; j < 4; ++j) {
      if (f2key(vv[j]) >= t50) {
        int p = atomicAdd(&s_cnt, 1);
        if (p < CAP) { cval[p] = vv[j]; cidx[p] = q * 4 + j; }
      }
    }
    reinterpret_cast<float4*>(rowp)[q] = z4;
  }
  if (tid == 0) {
    float l = rowp[V_DIM - 1];
    if (f2key(l) >= t50) {
      int p = atomicAdd(&s_cnt, 1);
      if (p < CAP) { cval[p] = l; cidx[p] = V_DIM - 1; }
    }
    rowp[V_DIM - 1] = 0.f;
  }
  __syncthreads();
  const int n = min(s_cnt, CAP);  // n >= TOPK guaranteed

  // parallel stable rank (val desc, idx asc)
  for (int i = tid; i < n; i += 256) {
    float vi = cval[i];
    int xi = cidx[i];
    int r = 0;
    for (int j = 0; j < n; ++j) {
      float vj = cval[j];
      if (vj > vi || (vj == vi && cidx[j] < xi)) ++r;
    }
    if (r < SCAP) { sval[r] = vi; sidx[r] = xi; }
  }
  __syncthreads();

  // exact top-k threshold + survivor count
  const float t = sval[TOPK - 1];
  for (int i = tid; i < n; i += 256)
    if (cval[i] >= t) atomicAdd(&s_nsurv, 1);
  __syncthreads();
  const int nsurv = min(s_nsurv, SCAP);

  // softmax numerators over survivors + top-p cutoff
  const float m = sval[0];
  for (int i = tid; i < nsurv; i += 256) pvals[i] = expf(sval[i] - m);
  __syncthreads();
  if (tid == 0) {
    float Z0 = 0.f;
    for (int i = 0; i < nsurv; ++i) Z0 += pvals[i];
    float cum = 0.f;
    int kc = 0;
    float Z2 = 0.f;
    for (int i = 0; i < nsurv; ++i) {
      cum += pvals[i] / Z0;
      if (cum > TOPP) break;
      kc = i + 1;
      Z2 += pvals[i];
    }
    s_kc = kc;
    s_invZ = (kc > 0) ? (1.f / Z2) : 0.f;
  }
  __syncthreads();
  const int kc = s_kc;
  const float invZ = s_invZ;

  // scatter per the reference's double-gather: out[rank(q)] = P(q)
  for (int q = tid; q < kc; q += 256) {
    int r = -1, less = 0;
    for (int s = 0; s < nsurv; ++s) {
      if (sidx[s] == q) r = s;
      if (sidx[s] < q) ++less;
    }
    int rank = (r >= 0) ? r : (nsurv + q - less);
    rowp[rank] = pvals[q] * invZ;
  }
}

// ----------------------------- launcher ------------------------------
extern "C" void kernel_launch(void* const* d_in, const int* in_sizes, int n_in,
                              void* d_out, int out_size, void* d_ws, size_t ws_size,
                              hipStream_t stream) {
  const float* X = (const float*)d_in[0];
  const float* W = (const float*)d_in[1];
  const float* Bv = (const float*)d_in[2];
  float* C = (float*)d_out;

  unsigned short* Xp = (unsigned short*)d_ws;
  unsigned short* Wp = Xp + (size_t)M_TOT * KP;
  unsigned* Tmax = (unsigned*)(Wp + (size_t)NPAD * KP);

  convx_kernel<<<(M_TOT * (K_DIM / 4) + 255) / 256, 256, 0, stream>>>(X, Xp);
  convw_kernel<<<(NPAD * (K_DIM / 4) + 255) / 256, 256, 0, stream>>>(W, Wp);
  mfma_gemm_kernel<<<NBM * NBN, 256, 0, stream>>>(Xp, Wp, Bv, C, Tmax);
  select_kernel<<<M_TOT, 256, 0, stream>>>(C, Tmax);
}

// Round 6
// 664.586 us; speedup vs baseline: 5.4694x; 1.1128x over previous
//
#include <hip/hip_runtime.h>
#include <math.h>

// Problem constants
#define TEMP 0.7f
#define TOPK 50
#define TOPP 0.9f
#define M_TOT 2048      // B*S
#define K_DIM 512       // H
#define V_DIM 50257     // vocab
#define NPAD 50304      // 393*128
#define KP 1536         // 3*K_DIM: [hi|hi|lo] x [hi|lo|hi]
#define BM 128
#define BN 128
#define BKE 64
#define NSTEP (KP / BKE)
#define NBN (NPAD / BN)  // 393 N-tiles
#define NBM (M_TOT / BM) // 16 M-tiles

typedef short s16x8 __attribute__((ext_vector_type(8)));
typedef float f32x4 __attribute__((ext_vector_type(4)));

#define MFMA_16x16x32_BF16(acc, va, vb) \
  asm("v_mfma_f32_16x16x32_bf16 %0, %1, %2, %0" : "+v"(acc) : "v"(va), "v"(vb))

__device__ __forceinline__ unsigned short bf16_rn(float x) {
  unsigned u = __float_as_uint(x);
  unsigned r = u + 0x7FFFu + ((u >> 16) & 1u);
  return (unsigned short)(r >> 16);
}
__device__ __forceinline__ float bf16_to_f(unsigned short h) {
  return __uint_as_float(((unsigned)h) << 16);
}
__device__ __forceinline__ unsigned f2key(float f) {
  unsigned u = __float_as_uint(f);
  return (u & 0x80000000u) ? ~u : (u | 0x80000000u);
}

// ---------------- conversion: X -> [hi|hi|lo], W -> [hi|lo|hi] ----------------
__global__ __launch_bounds__(256) void convx_kernel(const float* __restrict__ X,
                                                    unsigned short* __restrict__ Xp) {
  int idx = blockIdx.x * 256 + threadIdx.x;
  const int total = M_TOT * (K_DIM / 4);
  if (idx >= total) return;
  int row = idx >> 7;
  int q = idx & 127;
  const float4 v = reinterpret_cast<const float4*>(X)[idx];
  float vv[4] = {v.x, v.y, v.z, v.w};
  unsigned short hi[4], lo[4];
#pragma unroll
  for (int j = 0; j < 4; ++j) {
    hi[j] = bf16_rn(vv[j]);
    lo[j] = bf16_rn(vv[j] - bf16_to_f(hi[j]));
  }
  ushort4 h4 = make_ushort4(hi[0], hi[1], hi[2], hi[3]);
  ushort4 l4 = make_ushort4(lo[0], lo[1], lo[2], lo[3]);
  size_t base = (size_t)row * KP + q * 4;
  *reinterpret_cast<ushort4*>(Xp + base) = h4;
  *reinterpret_cast<ushort4*>(Xp + base + K_DIM) = h4;
  *reinterpret_cast<ushort4*>(Xp + base + 2 * K_DIM) = l4;
}

__global__ __launch_bounds__(256) void convw_kernel(const float* __restrict__ W,
                                                    unsigned short* __restrict__ Wp) {
  int idx = blockIdx.x * 256 + threadIdx.x;
  const int total = NPAD * (K_DIM / 4);
  if (idx >= total) return;
  int row = idx >> 7;
  int q = idx & 127;
  float4 v = make_float4(0.f, 0.f, 0.f, 0.f);
  if (row < V_DIM) v = reinterpret_cast<const float4*>(W)[(size_t)row * 128 + q];
  float vv[4] = {v.x, v.y, v.z, v.w};
  unsigned short hi[4], lo[4];
#pragma unroll
  for (int j = 0; j < 4; ++j) {
    hi[j] = bf16_rn(vv[j]);
    lo[j] = bf16_rn(vv[j] - bf16_to_f(hi[j]));
  }
  ushort4 h4 = make_ushort4(hi[0], hi[1], hi[2], hi[3]);
  ushort4 l4 = make_ushort4(lo[0], lo[1], lo[2], lo[3]);
  size_t base = (size_t)row * KP + q * 4;
  *reinterpret_cast<ushort4*>(Wp + base) = h4;
  *reinterpret_cast<ushort4*>(Wp + base + K_DIM) = l4;
  *reinterpret_cast<ushort4*>(Wp + base + 2 * K_DIM) = h4;
}

// ---------------- MFMA GEMM + per-(row, N-tile) max epilogue ----------------
// 2D grid, M fastest (round-4 order; XCD swizzle measured as a regression).
__global__ __launch_bounds__(256) void mfma_gemm_kernel(
    const unsigned short* __restrict__ Ap, const unsigned short* __restrict__ Bp,
    const float* __restrict__ Bv, float* __restrict__ C,
    unsigned* __restrict__ Tmax) {
  __shared__ __align__(16) unsigned char lds[32768];
  __shared__ unsigned umax[BM];
  const int tid = threadIdx.x;
  const int w = tid >> 6, lane = tid & 63;
  const int bm = blockIdx.x * BM;
  const int bni = blockIdx.y;
  const int bn = bni * BN;
  const int wr = w >> 1, wc = w & 1;

  f32x4 acc[4][4] = {};

  for (int step = 0; step < NSTEP; ++step) {
    const int k0 = step * BKE;
#pragma unroll
    for (int q = 0; q < 4; ++q) {
      int pp = ((w * 4 + q) << 10) + (lane << 4);
      int row = pp >> 7;
      int cb = (pp & 127) ^ ((row & 7) << 4);
      const unsigned short* ga = Ap + (size_t)(bm + row) * KP + k0 + (cb >> 1);
      __builtin_amdgcn_global_load_lds(
          (const __attribute__((address_space(1))) unsigned int*)ga,
          (__attribute__((address_space(3))) unsigned int*)(lds + pp), 16, 0, 0);
      const unsigned short* gb = Bp + (size_t)(bn + row) * KP + k0 + (cb >> 1);
      __builtin_amdgcn_global_load_lds(
          (const __attribute__((address_space(1))) unsigned int*)gb,
          (__attribute__((address_space(3))) unsigned int*)(lds + 16384 + pp), 16, 0, 0);
    }
    __syncthreads();
#pragma unroll
    for (int kk = 0; kk < 2; ++kk) {
      const int kbyte = kk * 64 + ((lane >> 4) << 4);
      s16x8 a[4], b[4];
#pragma unroll
      for (int i = 0; i < 4; ++i) {
        int row = (wr << 6) + (i << 4) + (lane & 15);
        int byte = (row << 7) + (kbyte ^ ((row & 7) << 4));
        a[i] = *reinterpret_cast<const s16x8*>(lds + byte);
      }
#pragma unroll
      for (int j = 0; j < 4; ++j) {
        int row = (wc << 6) + (j << 4) + (lane & 15);
        int byte = (row << 7) + (kbyte ^ ((row & 7) << 4));
        b[j] = *reinterpret_cast<const s16x8*>(lds + 16384 + byte);
      }
#pragma unroll
      for (int i = 0; i < 4; ++i)
#pragma unroll
        for (int j = 0; j < 4; ++j) MFMA_16x16x32_BF16(acc[i][j], a[i], b[j]);
    }
    __syncthreads();
  }

  if (tid < BM) umax[tid] = 0;
  __syncthreads();

  float mx[4][4];
#pragma unroll
  for (int i = 0; i < 4; ++i)
#pragma unroll
    for (int r = 0; r < 4; ++r) mx[i][r] = -INFINITY;

#pragma unroll
  for (int i = 0; i < 4; ++i) {
#pragma unroll
    for (int j = 0; j < 4; ++j) {
      int n = bn + (wc << 6) + (j << 4) + (lane & 15);
      if (n < V_DIM) {
        float bv = Bv[n];
#pragma unroll
        for (int r = 0; r < 4; ++r) {
          int m = bm + (wr << 6) + (i << 4) + ((lane >> 4) << 2) + r;
          float val = (acc[i][j][r] + bv) / TEMP;
          C[(size_t)m * V_DIM + n] = val;
          mx[i][r] = fmaxf(mx[i][r], val);
        }
      }
    }
  }
#pragma unroll
  for (int i = 0; i < 4; ++i) {
#pragma unroll
    for (int r = 0; r < 4; ++r) {
      float v = mx[i][r];
      v = fmaxf(v, __shfl_xor(v, 1));
      v = fmaxf(v, __shfl_xor(v, 2));
      v = fmaxf(v, __shfl_xor(v, 4));
      v = fmaxf(v, __shfl_xor(v, 8));
      if ((lane & 15) == 0)
        atomicMax(&umax[(wr << 6) + (i << 4) + ((lane >> 4) << 2) + r], f2key(v));
    }
  }
  __syncthreads();
  if (tid < BM) Tmax[(size_t)(bm + tid) * NBN + bni] = umax[tid];
}

// ---- per-row select: Tmax-guided gather (read only ~50 tiles) + pure-write zero
#define CAP 1024
#define SCAP 256

__global__ __launch_bounds__(256) void select_kernel(float* __restrict__ C,
                                                     const unsigned* __restrict__ Tmax) {
  const int row = blockIdx.x;
  float* rowp = C + (size_t)row * V_DIM;
  const int tid = threadIdx.x;

  __shared__ unsigned tk[NBN];
  __shared__ short ctile[NBN];  // candidate tiles (max >= t50); full capacity
  __shared__ unsigned s_t50;
  __shared__ float cval[CAP];
  __shared__ int cidx[CAP];
  __shared__ float sval[SCAP];
  __shared__ int sidx[SCAP];
  __shared__ float pvals[SCAP];
  __shared__ int s_cnt, s_ntile, s_nsurv, s_kc;
  __shared__ float s_invZ;

  // t50 = 50th-largest tile max (key space); t50 <= true top-k threshold tau
  for (int i = tid; i < NBN; i += 256) tk[i] = Tmax[(size_t)row * NBN + i];
  if (tid == 0) { s_cnt = 0; s_ntile = 0; s_nsurv = 0; }
  __syncthreads();
  for (int i = tid; i < NBN; i += 256) {
    unsigned ki = tk[i];
    int r = 0;
    for (int j = 0; j < NBN; ++j) {
      unsigned kj = tk[j];
      r += (kj > ki) || (kj == ki && j < i);
    }
    if (r == TOPK - 1) s_t50 = ki;
  }
  __syncthreads();
  const unsigned t50 = s_t50;

  // candidate tiles: any tile that can hold a value >= t50
  for (int i = tid; i < NBN; i += 256) {
    if (tk[i] >= t50) {
      int p = atomicAdd(&s_ntile, 1);
      ctile[p] = (short)i;
    }
  }
  __syncthreads();
  const int ntile = s_ntile;  // ~50

  // gather candidates from only those tiles (~50*128 reads)
  for (int e = tid; e < ntile * BN; e += 256) {
    int ti = ctile[e >> 7];
    int n = ti * BN + (e & 127);
    if (n < V_DIM) {
      float l = rowp[n];
      if (f2key(l) >= t50) {
        int p = atomicAdd(&s_cnt, 1);
        if (p < CAP) { cval[p] = l; cidx[p] = n; }
      }
    }
  }
  __syncthreads();
  const int n = min(s_cnt, CAP);  // n >= TOPK guaranteed

  // zero the whole row: pure stream write, no read
  {
    const float4 z4 = make_float4(0.f, 0.f, 0.f, 0.f);
    const int NQ = V_DIM >> 2;
    for (int q = tid; q < NQ; q += 256) reinterpret_cast<float4*>(rowp)[q] = z4;
    if (tid == 0) rowp[V_DIM - 1] = 0.f;
  }

  // parallel stable rank (val desc, idx asc)
  for (int i = tid; i < n; i += 256) {
    float vi = cval[i];
    int xi = cidx[i];
    int r = 0;
    for (int j = 0; j < n; ++j) {
      float vj = cval[j];
      if (vj > vi || (vj == vi && cidx[j] < xi)) ++r;
    }
    if (r < SCAP) { sval[r] = vi; sidx[r] = xi; }
  }
  __syncthreads();

  // exact top-k threshold + survivor count (float compares, like ref)
  const float t = sval[TOPK - 1];
  for (int i = tid; i < n; i += 256)
    if (cval[i] >= t) atomicAdd(&s_nsurv, 1);
  __syncthreads();
  const int nsurv = min(s_nsurv, SCAP);

  // softmax numerators over survivors + top-p cutoff
  const float m = sval[0];
  for (int i = tid; i < nsurv; i += 256) pvals[i] = expf(sval[i] - m);
  __syncthreads();
  if (tid == 0) {
    float Z0 = 0.f;
    for (int i = 0; i < nsurv; ++i) Z0 += pvals[i];
    float cum = 0.f;
    int kc = 0;
    float Z2 = 0.f;
    for (int i = 0; i < nsurv; ++i) {
      cum += pvals[i] / Z0;
      if (cum > TOPP) break;
      kc = i + 1;
      Z2 += pvals[i];
    }
    s_kc = kc;
    s_invZ = (kc > 0) ? (1.f / Z2) : 0.f;
  }
  __syncthreads();
  const int kc = s_kc;
  const float invZ = s_invZ;

  // scatter per the reference's double-gather: out[rank(q)] = P(q)
  for (int q = tid; q < kc; q += 256) {
    int r = -1, less = 0;
    for (int s = 0; s < nsurv; ++s) {
      if (sidx[s] == q) r = s;
      if (sidx[s] < q) ++less;
    }
    int rank = (r >= 0) ? r : (nsurv + q - less);
    rowp[rank] = pvals[q] * invZ;
  }
}

// ----------------------------- launcher ------------------------------
extern "C" void kernel_launch(void* const* d_in, const int* in_sizes, int n_in,
                              void* d_out, int out_size, void* d_ws, size_t ws_size,
                              hipStream_t stream) {
  const float* X = (const float*)d_in[0];
  const float* W = (const float*)d_in[1];
  const float* Bv = (const float*)d_in[2];
  float* C = (float*)d_out;

  unsigned short* Xp = (unsigned short*)d_ws;
  unsigned short* Wp = Xp + (size_t)M_TOT * KP;
  unsigned* Tmax = (unsigned*)(Wp + (size_t)NPAD * KP);

  convx_kernel<<<(M_TOT * (K_DIM / 4) + 255) / 256, 256, 0, stream>>>(X, Xp);
  convw_kernel<<<(NPAD * (K_DIM / 4) + 255) / 256, 256, 0, stream>>>(W, Wp);
  dim3 g(NBM, NBN);  // M fastest: consecutive blocks share a B panel
  mfma_gemm_kernel<<<g, 256, 0, stream>>>(Xp, Wp, Bv, C, Tmax);
  select_kernel<<<M_TOT, 256, 0, stream>>>(C, Tmax);
}